// Round 17
// baseline (674.495 us; speedup 1.0000x reference)
//
#include <hip/hip_runtime.h>
#include <hip/hip_bf16.h>
#include <math.h>

#define S_N 50000
#define E_N 20000
#define K_N 128
#define D_N 128
#define NE_N 800000
#define B_N 8192
#define L_N 3
#define GATE_TILES (NE_N / 64)
#define NB_S 782   // ceil(50000/64)
#define NB_E 313   // ceil(20000/64)
#define BPAD 464   // scan reserve base: per bucket p = (v+BPAD+15)&~15 <= v+479
#define BSLACK 480 // allocation slack per bucket (strictly > 479)

typedef __attribute__((ext_vector_type(4))) float floatx4;
typedef __attribute__((ext_vector_type(8))) short short8v;

__device__ __forceinline__ unsigned short f2bf(float x) {
  unsigned int u = __float_as_uint(x);
  u += 0x7FFFu + ((u >> 16) & 1u);
  return (unsigned short)(u >> 16);
}
__device__ __forceinline__ float bf2f(unsigned short u) {
  return __uint_as_float(((unsigned int)u) << 16);
}
__device__ __forceinline__ float sigm(float z) { return 1.0f / (1.0f + __expf(-z)); }

// OCP e4m3fn, round-to-nearest-even, saturating
__device__ __forceinline__ unsigned char f2e4m3(float x) {
  unsigned int u = __float_as_uint(x);
  unsigned char s = (unsigned char)((u >> 24) & 0x80);
  int e = (int)((u >> 23) & 0xFF) - 127;
  unsigned int m = u & 0x7FFFFF;
  if (((u >> 23) & 0xFF) == 0) return s;
  if (e >= 9) return s | 0x7E;
  if (e < -10) return s;
  if (e >= -6) {
    unsigned int keep = m >> 20;
    unsigned int rest = m & 0xFFFFF;
    if (rest > 0x80000u || (rest == 0x80000u && (keep & 1))) keep++;
    if (keep == 8) { keep = 0; e++; if (e >= 9) return s | 0x7E; }
    unsigned char b = (unsigned char)(s | ((e + 7) << 3) | keep);
    if ((b & 0x7F) == 0x7F) b = s | 0x7E;
    return b;
  }
  int shift = -6 - e;
  unsigned int full = 0x800000u | m;
  unsigned int q = full >> (20 + shift);
  unsigned int rest = full & ((1u << (20 + shift)) - 1);
  unsigned int half = 1u << (19 + shift);
  if (rest > half || (rest == half && (q & 1))) q++;
  if (q == 8) return s | 0x08;
  return (unsigned char)(s | q);
}
__device__ __forceinline__ unsigned int pk4_fp8(float4 v) {
  return (unsigned int)f2e4m3(v.x) | ((unsigned int)f2e4m3(v.y) << 8) |
         ((unsigned int)f2e4m3(v.z) << 16) | ((unsigned int)f2e4m3(v.w) << 24);
}

// ---------------- prep: fp8 W1s, |pw|^T, keT ----------------
__global__ void prep_kernel(const float* __restrict__ W1_l1, const float* __restrict__ W1_l0,
                            const float* __restrict__ pw1, const float* __restrict__ pw2,
                            const float* __restrict__ pw3, const float* __restrict__ ke,
                            unsigned int* __restrict__ w1f8_1, unsigned int* __restrict__ w1f8_0,
                            float* __restrict__ pw1T, float* __restrict__ pw2T,
                            float* __restrict__ pw3a, float* __restrict__ keT) {
  int i = blockIdx.x * blockDim.x + threadIdx.x;
  if (i < 8192) { w1f8_1[i] = pk4_fp8(((const float4*)W1_l1)[i]); return; }
  i -= 8192;
  if (i < 8192) { w1f8_0[i] = pk4_fp8(((const float4*)W1_l0)[i]); return; }
  i -= 8192;
  if (i < 32768) { int d = i >> 8, j = i & 255; pw1T[i] = fabsf(pw1[j * 128 + d]); return; }
  i -= 32768;
  if (i < 32768) { int d = i >> 7, j = i & 127; pw2T[i] = fabsf(pw2[j * 256 + d]); return; }
  i -= 32768;
  if (i < 128) { pw3a[i] = fabsf(pw3[i]); return; }
  i -= 128;
  if (i < 16384) { int d = i >> 7, k = i & 127; keT[i] = ke[k * 128 + d]; return; }
}

// ---------------- init: bf16 tables (spmm L0) + fp8 tables (gate) ----------------
__global__ void init_bf_kernel(const float* __restrict__ se, const float* __restrict__ ee,
                               unsigned short* __restrict__ sbf, unsigned short* __restrict__ ebf,
                               unsigned int* __restrict__ sf8, unsigned int* __restrict__ ef8) {
  int i = blockIdx.x * blockDim.x + threadIdx.x;
  const int nS4 = S_N * 32, nE4 = E_N * 32;
  if (i < nS4) {
    float4 v = ((const float4*)se)[i];
    unsigned int lo = (unsigned int)f2bf(v.x) | ((unsigned int)f2bf(v.y) << 16);
    unsigned int hi = (unsigned int)f2bf(v.z) | ((unsigned int)f2bf(v.w) << 16);
    ((uint2*)sbf)[i] = make_uint2(lo, hi);
    sf8[i] = pk4_fp8(v);
    return;
  }
  i -= nS4;
  if (i < nE4) {
    float4 v = ((const float4*)ee)[i];
    unsigned int lo = (unsigned int)f2bf(v.x) | ((unsigned int)f2bf(v.y) << 16);
    unsigned int hi = (unsigned int)f2bf(v.z) | ((unsigned int)f2bf(v.w) << 16);
    ((uint2*)ebf)[i] = make_uint2(lo, hi);
    ef8[i] = pk4_fp8(v);
  }
}

__global__ void zero_kernel(int* __restrict__ p, int n) {
  int i = blockIdx.x * blockDim.x + threadIdx.x;
  if (i < n) p[i] = 0;
}

// ---------------- bucket histogram (64-row buckets) ----------------
__global__ __launch_bounds__(256)
void histB_kernel(const int* __restrict__ u1, const int* __restrict__ i1,
                  const int* __restrict__ u0, const int* __restrict__ i0,
                  int* __restrict__ gHistS, int* __restrict__ gHistE) {
  __shared__ int hS[NB_S], hE[NB_E];
  int t = threadIdx.x;
  for (int b = t; b < NB_S; b += 256) hS[b] = 0;
  for (int b = t; b < NB_E; b += 256) hE[b] = 0;
  __syncthreads();
  int e0 = blockIdx.x * 2048;
  for (int k = 0; k < 8; ++k) {
    int e = e0 + k * 256 + t;
    if (e < NE_N) {
      atomicAdd(&hS[u1[e] >> 6], 1);
      atomicAdd(&hS[u0[e] >> 6], 1);
      atomicAdd(&hE[i1[e] >> 6], 1);
      atomicAdd(&hE[i0[e] >> 6], 1);
    }
  }
  __syncthreads();
  for (int b = t; b < NB_S; b += 256) if (hS[b]) atomicAdd(&gHistS[b], hS[b]);
  for (int b = t; b < NB_E; b += 256) if (hE[b]) atomicAdd(&gHistE[b], hE[b]);
}

// ------- scan buckets: packed bases+cursors AND padded-region bases -------
__global__ __launch_bounds__(128)
void scanB_kernel(const int* __restrict__ gHistS, int* __restrict__ baseS,
                  int* __restrict__ gCurS, int* __restrict__ basePS,
                  const int* __restrict__ gHistE, int* __restrict__ baseE,
                  int* __restrict__ gCurE, int* __restrict__ basePE) {
  int w = threadIdx.x >> 6, l = threadIdx.x & 63;
  int n = w ? NB_E : NB_S;
  const int* src = w ? gHistE : gHistS;
  int* bs  = w ? baseE  : baseS;
  int* cur = w ? gCurE  : gCurS;
  int* bsP = w ? basePE : basePS;
  int carry = 0, carryP = 0;
  for (int base = 0; base < n; base += 64) {
    int i = base + l;
    int v = (i < n) ? src[i] : 0;
    int p = (i < n) ? ((v + BPAD + 15) & ~15) : 0;
    int x = v, y = p;
#pragma unroll
    for (int o = 1; o < 64; o <<= 1) {
      int xx = __shfl_up(x, o, 64);
      int yy = __shfl_up(y, o, 64);
      if (l >= o) { x += xx; y += yy; }
    }
    if (i < n) {
      int ex = carry + x - v;
      bs[i] = ex; cur[i] = ex;
      bsP[i] = carryP + y - p;
    }
    carry += __shfl(x, 63, 64);
    carryP += __shfl(y, 63, 64);
  }
  if (l == 0) { bs[n] = carry; bsP[n] = carryP; }
}

// ------- edge gate: merged polarities, DOUBLE-BUFFERED (T14 async-stage) -------
__global__ __launch_bounds__(512, 2)
void gate_kernel(const int* __restrict__ eu1, const int* __restrict__ ei1,
                 const int* __restrict__ eu0, const int* __restrict__ ei0,
                 const unsigned char* __restrict__ sf8, const unsigned char* __restrict__ ef8,
                 const unsigned char* __restrict__ w1f8_1, const unsigned char* __restrict__ w1f8_0,
                 const float* __restrict__ b1_1, const float* __restrict__ w2_1,
                 const float* __restrict__ b2_1,
                 const float* __restrict__ b1_0, const float* __restrict__ w2_0,
                 const float* __restrict__ b2_0,
                 float* __restrict__ logit1, float* __restrict__ logit0) {
  __shared__ unsigned char Xl[2][64 * 272];
  __shared__ float plds[8][16];
  const int* eu; const int* ei; const unsigned char* w1f8;
  const float *b1p, *w2p, *b2p; float* lg;
  if (blockIdx.x < 2048) {
    eu = eu1; ei = ei1; w1f8 = w1f8_1; b1p = b1_1; w2p = w2_1; b2p = b2_1; lg = logit1;
  } else {
    eu = eu0; ei = ei0; w1f8 = w1f8_0; b1p = b1_0; w2p = w2_0; b2p = b2_0; lg = logit0;
  }
  int bb = blockIdx.x & 2047;
  int t = threadIdx.x;
  int wv = t >> 6, l = t & 63;
  int sub = l & 15, grp = l >> 4;
  int nh = wv & 1, rg = wv >> 1;
  int el = t >> 3, q = t & 7;

  long bfrag[4][8];
#pragma unroll
  for (int nt = 0; nt < 4; ++nt) {
    int col = nh * 64 + nt * 16 + sub;
#pragma unroll
    for (int ks = 0; ks < 8; ++ks)
      bfrag[nt][ks] = *(const long*)&w1f8[(col << 8) + ks * 32 + grp * 8];
  }
  float b1v[4], w2v[4];
#pragma unroll
  for (int nt = 0; nt < 4; ++nt) {
    int col = nh * 64 + nt * 16 + sub;
    b1v[nt] = b1p[col];
    w2v[nt] = w2p[col];
  }
  float b2s = b2p[0];

  uint4 c0, c1;
  {  // prologue: stage tile bb into buffer 0
    int eIdx = bb * 64 + el;
    const unsigned char* srcrow = (q < 4)
        ? sf8 + (size_t)eu[eIdx] * 128 + q * 32
        : ef8 + (size_t)ei[eIdx] * 128 + (q - 4) * 32;
    c0 = ((const uint4*)srcrow)[0];
    c1 = ((const uint4*)srcrow)[1];
    *(uint4*)&Xl[0][el * 272 + q * 32] = c0;
    *(uint4*)&Xl[0][el * 272 + q * 32 + 16] = c1;
  }
  int parity = 0;
  for (int tile = bb; tile < GATE_TILES; tile += 2048) {
    int nxt = tile + 2048;
    bool hasNext = (nxt < GATE_TILES);
    if (hasNext) {  // issue next tile's gathers early: latency hides under MFMA below
      int eIdx = nxt * 64 + el;
      const unsigned char* srcrow = (q < 4)
          ? sf8 + (size_t)eu[eIdx] * 128 + q * 32
          : ef8 + (size_t)ei[eIdx] * 128 + (q - 4) * 32;
      c0 = ((const uint4*)srcrow)[0];
      c1 = ((const uint4*)srcrow)[1];
    }
    __syncthreads();   // Xl[parity] fully staged

    floatx4 zero4 = {0.f, 0.f, 0.f, 0.f};
    floatx4 acc[4] = {zero4, zero4, zero4, zero4};
#pragma unroll
    for (int ks = 0; ks < 8; ++ks) {
      long a = *(const long*)&Xl[parity][(rg * 16 + sub) * 272 + ks * 32 + grp * 8];
#pragma unroll
      for (int nt = 0; nt < 4; ++nt)
        acc[nt] = __builtin_amdgcn_mfma_f32_16x16x32_fp8_fp8(a, bfrag[nt][ks], acc[nt], 0, 0, 0);
    }
    float p0 = 0, p1 = 0, p2 = 0, p3 = 0;
#pragma unroll
    for (int nt = 0; nt < 4; ++nt) {
      float bb2 = b1v[nt], ww = w2v[nt];
      p0 += fmaxf(acc[nt][0] + bb2, 0.0f) * ww;
      p1 += fmaxf(acc[nt][1] + bb2, 0.0f) * ww;
      p2 += fmaxf(acc[nt][2] + bb2, 0.0f) * ww;
      p3 += fmaxf(acc[nt][3] + bb2, 0.0f) * ww;
    }
#pragma unroll
    for (int m = 1; m < 16; m <<= 1) {
      p0 += __shfl_xor(p0, m, 64);
      p1 += __shfl_xor(p1, m, 64);
      p2 += __shfl_xor(p2, m, 64);
      p3 += __shfl_xor(p3, m, 64);
    }
    if (sub < 4) {
      float pv = (sub == 0) ? p0 : (sub == 1) ? p1 : (sub == 2) ? p2 : p3;
      plds[wv][grp * 4 + sub] = pv;
    }
    __syncthreads();   // plds ready; all reads of Xl[parity] done
    if (wv == 0)
      lg[tile * 64 + l] = plds[(l >> 4) * 2][l & 15] + plds[(l >> 4) * 2 + 1][l & 15] + b2s;
    if (hasNext) {     // write staged regs into the other buffer (its readers finished last iter)
      *(uint4*)&Xl[parity ^ 1][el * 272 + q * 32] = c0;
      *(uint4*)&Xl[parity ^ 1][el * 272 + q * 32 + 16] = c1;
    }
    parity ^= 1;
  }
}

// ------- append (gatefin fused): compute v inline from logit/eps/val, bucket-append -------
__global__ __launch_bounds__(256)
void append_kernel(const int* __restrict__ u1, const int* __restrict__ i1,
                   const int* __restrict__ u0, const int* __restrict__ i0,
                   const float* __restrict__ logit1, const float* __restrict__ logit0,
                   const float* __restrict__ ui1_val, const float* __restrict__ iu1_val,
                   const float* __restrict__ eps_ui1, const float* __restrict__ eps_iu1,
                   const float* __restrict__ ui0_val, const float* __restrict__ iu0_val,
                   const float* __restrict__ eps_ui0, const float* __restrict__ eps_iu0,
                   int* __restrict__ gCurS, int* __restrict__ gCurE,
                   int2* __restrict__ recS, int2* __restrict__ recE) {
  __shared__ int hS[NB_S], hE[NB_E];
  int t = threadIdx.x;
  for (int b = t; b < NB_S; b += 256) hS[b] = 0;
  for (int b = t; b < NB_E; b += 256) hE[b] = 0;
  __syncthreads();
  int e0 = blockIdx.x * 2048;
  for (int k = 0; k < 8; ++k) {
    int e = e0 + k * 256 + t;
    if (e < NE_N) {
      atomicAdd(&hS[u1[e] >> 6], 1);
      atomicAdd(&hS[u0[e] >> 6], 1);
      atomicAdd(&hE[i1[e] >> 6], 1);
      atomicAdd(&hE[i0[e] >> 6], 1);
    }
  }
  __syncthreads();
  for (int b = t; b < NB_S; b += 256) { int c = hS[b]; hS[b] = c ? atomicAdd(&gCurS[b], c) : 0; }
  for (int b = t; b < NB_E; b += 256) { int c = hE[b]; hE[b] = c ? atomicAdd(&gCurE[b], c) : 0; }
  __syncthreads();
  for (int k = 0; k < 8; ++k) {
    int e = e0 + k * 256 + t;
    if (e < NE_N) {
      int a = u1[e], b = i1[e], c = u0[e], d = i0[e];
      float lg1 = logit1[e], lg0 = logit0[e];
      float ep, g, s2;
      ep = fminf(fmaxf(eps_ui1[e], 1e-6f), 1.0f - 1e-6f);
      g = __logf(ep) - log1pf(-ep);
      s2 = 1.0f / (1.0f + __expf(-(lg1 + g) * 5.0f));
      float v_ui1 = ui1_val[e] * (0.3f * s2 + 0.7f);
      ep = fminf(fmaxf(eps_iu1[e], 1e-6f), 1.0f - 1e-6f);
      g = __logf(ep) - log1pf(-ep);
      s2 = 1.0f / (1.0f + __expf(-(lg1 + g) * 5.0f));
      float v_iu1 = iu1_val[e] * (0.3f * s2 + 0.7f);
      ep = fminf(fmaxf(eps_ui0[e], 1e-6f), 1.0f - 1e-6f);
      g = __logf(ep) - log1pf(-ep);
      s2 = 1.0f / (1.0f + __expf(-(lg0 + g) * 5.0f));
      float v_ui0 = ui0_val[e] * (0.3f * s2 + 0.7f);
      ep = fminf(fmaxf(eps_iu0[e], 1e-6f), 1.0f - 1e-6f);
      g = __logf(ep) - log1pf(-ep);
      s2 = 1.0f / (1.0f + __expf(-(lg0 + g) * 5.0f));
      float v_iu0 = iu0_val[e] * (0.3f * s2 + 0.7f);
      int s;
      s = atomicAdd(&hS[a >> 6], 1); recS[s] = make_int2(((a & 63) << 16) | b, __float_as_int(v_ui1));
      s = atomicAdd(&hE[b >> 6], 1); recE[s] = make_int2(((b & 63) << 16) | a, __float_as_int(v_iu1));
      s = atomicAdd(&hS[c >> 6], 1); recS[s] = make_int2(((c & 63) << 16) | d, __float_as_int(v_ui0));
      s = atomicAdd(&hE[d >> 6], 1); recE[s] = make_int2(((d & 63) << 16) | c, __float_as_int(v_iu0));
    }
  }
}

// ---- per-bucket counting sort by SRC COL CHUNK (col>>9), int2 -> int2, once ----
// Groups each bucket's records by 512-row source regions so spmm sweeps sources L2-locally.
__global__ __launch_bounds__(256)
void sortCol_kernel(const int* __restrict__ baseIn, const int2* __restrict__ rin_all,
                    int2* __restrict__ rout_all) {
  __shared__ int cnt2[128], incl[128], cur2[128];
  int b = blockIdx.x, t = threadIdx.x;
  int bi = baseIn[b], cnt = baseIn[b + 1] - bi;
  const int2* rin = rin_all + bi;
  int2* rout = rout_all + bi;
  if (t < 128) cnt2[t] = 0;
  __syncthreads();
  for (int j = t; j < cnt; j += 256) atomicAdd(&cnt2[(rin[j].x & 0xFFFF) >> 9], 1);
  __syncthreads();
  if (t < 128) {
    int l = t & 63;
    int v = cnt2[t];
    int x = v;
#pragma unroll
    for (int o = 1; o < 64; o <<= 1) { int y = __shfl_up(x, o, 64); if (l >= o) x += y; }
    incl[t] = x;
  }
  __syncthreads();
  if (t < 128) {
    int ex = incl[t] - cnt2[t];
    if (t >= 64) ex += incl[63];
    cur2[t] = ex;
  }
  __syncthreads();
  for (int j = t; j < cnt; j += 256) {
    int2 rc = rin[j];
    int slot = atomicAdd(&cur2[(rc.x & 0xFFFF) >> 9], 1);
    rout[slot] = rc;
  }
}

// ---- per-bucket counting sort by dst ROW into padded per-row segments; EMIT 4B records ----
// out record: (col 16b) | (val bf16 << 16); rows padded to multiple of 8 with 0 (col 0, val +0.0)
__global__ __launch_bounds__(256)
void sortRow_kernel(const int* __restrict__ baseIn, const int* __restrict__ basePad,
                    const int2* __restrict__ rin_all, int* __restrict__ rout_all,
                    int* __restrict__ rowPtr, int* __restrict__ rowCnt8, int nRowsTot) {
  __shared__ int cntR[64], offR[64], curR[64];
  int b = blockIdx.x, t = threadIdx.x;
  int bi = baseIn[b], cnt = baseIn[b + 1] - bi;
  int bo = basePad[b];
  int row0 = b * 64;
  const int2* rin = rin_all + bi;
  int* rout = rout_all + bo;
  if (t < 64) cntR[t] = 0;
  __syncthreads();
  for (int j = t; j < cnt; j += 256) atomicAdd(&cntR[(rin[j].x >> 16) & 63], 1);
  __syncthreads();
  if (t < 64) {
    int p = (cntR[t] + 7) & ~7;
    int x = p;
#pragma unroll
    for (int o = 1; o < 64; o <<= 1) { int y = __shfl_up(x, o, 64); if (t >= o) x += y; }
    int ex = x - p;
    offR[t] = ex; curR[t] = ex;
    if (row0 + t < nRowsTot) {
      rowPtr[row0 + t] = bo + ex;
      rowCnt8[row0 + t] = p >> 3;
    }
  }
  __syncthreads();
  for (int j = t; j < cnt; j += 256) {  // ascending j preserves col-chunk order approximately
    int2 rc = rin[j];
    int r = (rc.x >> 16) & 63;
    int slot = atomicAdd(&curR[r], 1);
    rout[slot] = (rc.x & 0xFFFF) | ((int)f2bf(__int_as_float(rc.y)) << 16);
  }
  __syncthreads();
  if (t < 64) {
    int c = cntR[t], p = (c + 7) & ~7, o = offR[t];
    for (int j = c; j < p; ++j) rout[o + j] = 0;
  }
}

// ---- spmm CSR bf16: wave per dst row, 8 records in flight; 4B records (col|val-bf16) ----
__global__ __launch_bounds__(256)
void spmm_csr_kernel(const int* __restrict__ rowPtrS, const int* __restrict__ rowCnt8S,
                     const int* __restrict__ rec4S,
                     const int* __restrict__ rowPtrE, const int* __restrict__ rowCnt8E,
                     const int* __restrict__ rec4E,
                     const unsigned short* __restrict__ scur, const unsigned short* __restrict__ ecur,
                     unsigned short* __restrict__ snxt, unsigned short* __restrict__ enxt) {
  int gw = (blockIdx.x * 256 + threadIdx.x) >> 6;
  int l = threadIdx.x & 63;
  int g = l >> 3, lane8 = l & 7;
  if (gw >= S_N + E_N) return;
  const int* rec; const unsigned short* src; unsigned short* dst;
  const int* rp; const int* rc8; int r;
  if (gw < S_N) { r = gw;       rp = rowPtrS; rc8 = rowCnt8S; rec = rec4S; src = ecur; dst = snxt; }
  else          { r = gw - S_N; rp = rowPtrE; rc8 = rowCnt8E; rec = rec4E; src = scur; dst = enxt; }
  int s0 = rp[r], n8 = rc8[r];
  float acc[16];
#pragma unroll
  for (int i = 0; i < 16; ++i) acc[i] = 0.f;
  for (int k = 0; k < n8; ++k) {
    int e = rec[s0 + k * 8 + g];
    float val = bf2f((unsigned short)(e >> 16));
    const uint4* rowp = (const uint4*)(src + (size_t)(e & 0xFFFF) * 128);
    uint4 q0 = rowp[lane8 * 2];
    uint4 q1 = rowp[lane8 * 2 + 1];
#pragma unroll
    for (int i = 0; i < 4; ++i) {
      unsigned int w = ((const unsigned int*)&q0)[i];
      acc[2 * i]     = fmaf(val, bf2f((unsigned short)(w & 0xFFFF)), acc[2 * i]);
      acc[2 * i + 1] = fmaf(val, bf2f((unsigned short)(w >> 16)),    acc[2 * i + 1]);
    }
#pragma unroll
    for (int i = 0; i < 4; ++i) {
      unsigned int w = ((const unsigned int*)&q1)[i];
      acc[8 + 2 * i]     = fmaf(val, bf2f((unsigned short)(w & 0xFFFF)), acc[8 + 2 * i]);
      acc[8 + 2 * i + 1] = fmaf(val, bf2f((unsigned short)(w >> 16)),    acc[8 + 2 * i + 1]);
    }
  }
#pragma unroll
  for (int m = 8; m < 64; m <<= 1) {
#pragma unroll
    for (int i = 0; i < 16; ++i) acc[i] += __shfl_xor(acc[i], m, 64);
  }
  if (g == 0) {
    size_t base = (size_t)r * 128 + lane8 * 16;
    short8v o0, o1;
#pragma unroll
    for (int i = 0; i < 8; ++i) { o0[i] = (short)f2bf(acc[i]); o1[i] = (short)f2bf(acc[8 + i]); }
    *(short8v*)(dst + base) = o0;
    *(short8v*)(dst + base + 8) = o1;
  }
}

// ------- head 1: gather-sum 4 bf16 layer tables per side -------
__global__ __launch_bounds__(256)
void head1_kernel(const int* __restrict__ stu_id, const int* __restrict__ exer_id,
                  const float* __restrict__ kn,
                  const unsigned short* __restrict__ sT0, const unsigned short* __restrict__ sT1,
                  const unsigned short* __restrict__ sT2, const unsigned short* __restrict__ sT3,
                  const unsigned short* __restrict__ eT0, const unsigned short* __restrict__ eT1,
                  const unsigned short* __restrict__ eT2, const unsigned short* __restrict__ eT3,
                  const float* __restrict__ keT,
                  const float* __restrict__ stub, const float* __restrict__ exeb,
                  const float* __restrict__ disc, float* __restrict__ xbuf) {
  __shared__ float srw[4][128], erw[4][128];
  int wv = threadIdx.x >> 6, l = threadIdx.x & 63;
  int b = blockIdx.x * 4 + wv;
  int sid = stu_id[b], eid = exer_id[b];
  size_t so = (size_t)sid * 128, eo = (size_t)eid * 128;
  float sx = 0.f, sy = 0.f, ex = 0.f, ey = 0.f;
  unsigned int w;
  w = ((const unsigned int*)(sT0 + so))[l]; sx += bf2f((unsigned short)(w & 0xFFFF)); sy += bf2f((unsigned short)(w >> 16));
  w = ((const unsigned int*)(sT1 + so))[l]; sx += bf2f((unsigned short)(w & 0xFFFF)); sy += bf2f((unsigned short)(w >> 16));
  w = ((const unsigned int*)(sT2 + so))[l]; sx += bf2f((unsigned short)(w & 0xFFFF)); sy += bf2f((unsigned short)(w >> 16));
  w = ((const unsigned int*)(sT3 + so))[l]; sx += bf2f((unsigned short)(w & 0xFFFF)); sy += bf2f((unsigned short)(w >> 16));
  w = ((const unsigned int*)(eT0 + eo))[l]; ex += bf2f((unsigned short)(w & 0xFFFF)); ey += bf2f((unsigned short)(w >> 16));
  w = ((const unsigned int*)(eT1 + eo))[l]; ex += bf2f((unsigned short)(w & 0xFFFF)); ey += bf2f((unsigned short)(w >> 16));
  w = ((const unsigned int*)(eT2 + eo))[l]; ex += bf2f((unsigned short)(w & 0xFFFF)); ey += bf2f((unsigned short)(w >> 16));
  w = ((const unsigned int*)(eT3 + eo))[l]; ex += bf2f((unsigned short)(w & 0xFFFF)); ey += bf2f((unsigned short)(w >> 16));
  srw[wv][2 * l] = sx * 0.25f; srw[wv][2 * l + 1] = sy * 0.25f;
  erw[wv][2 * l] = ex * 0.25f; erw[wv][2 * l + 1] = ey * 0.25f;
  __syncthreads();
  float s0 = 0, s1 = 0, d0 = 0, d1 = 0;
  for (int d = 0; d < 128; ++d) {
    float sd = srw[wv][d], ed = erw[wv][d];
    float ka = keT[d * 128 + l], kb = keT[d * 128 + l + 64];
    s0 = fmaf(sd, ka, s0); s1 = fmaf(sd, kb, s1);
    d0 = fmaf(ed, ka, d0); d1 = fmaf(ed, kb, d1);
  }
  float sbv = stub[sid], ebv = exeb[eid];
  float edv = sigm(disc[eid]);
  float st0 = sigm(s0 + sbv), st1 = sigm(s1 + sbv);
  float df0 = sigm(d0 + ebv), df1 = sigm(d1 + ebv);
  xbuf[(size_t)b * 128 + l]      = edv * (st0 - df0) * kn[(size_t)b * 128 + l];
  xbuf[(size_t)b * 128 + l + 64] = edv * (st1 - df1) * kn[(size_t)b * 128 + l + 64];
}

// ---------------- head 2: PosLinear MLP ----------------
__global__ __launch_bounds__(256)
void head2_kernel(const float* __restrict__ xbuf, const float* __restrict__ pw1T,
                  const float* __restrict__ pb1, const float* __restrict__ pw2T,
                  const float* __restrict__ pb2, const float* __restrict__ pw3a,
                  const float* __restrict__ pb3, float* __restrict__ out) {
  __shared__ float xs[4][128], h1s[4][256], h2s[4][128];
  int wv = threadIdx.x >> 6, l = threadIdx.x & 63;
  int b = blockIdx.x * 4 + wv;
  xs[wv][l] = xbuf[(size_t)b * 128 + l];
  xs[wv][l + 64] = xbuf[(size_t)b * 128 + l + 64];
  __syncthreads();
#pragma unroll
  for (int q = 0; q < 4; ++q) {
    int j = q * 64 + l;
    float acc = 0.f;
    for (int d = 0; d < 128; ++d) acc = fmaf(xs[wv][d], pw1T[d * 256 + j], acc);
    h1s[wv][j] = sigm(acc + pb1[j]);
  }
  __syncthreads();
#pragma unroll
  for (int q = 0; q < 2; ++q) {
    int j = q * 64 + l;
    float acc = 0.f;
    for (int d = 0; d < 256; ++d) acc = fmaf(h1s[wv][d], pw2T[d * 128 + j], acc);
    h2s[wv][j] = sigm(acc + pb2[j]);
  }
  __syncthreads();
  float p = h2s[wv][l] * pw3a[l] + h2s[wv][l + 64] * pw3a[l + 64];
#pragma unroll
  for (int m = 1; m < 64; m <<= 1) p += __shfl_xor(p, m, 64);
  if (l == 0) out[b] = sigm(p + pb3[0]);
}

extern "C" void kernel_launch(void* const* d_in, const int* in_sizes, int n_in,
                              void* d_out, int out_size, void* d_ws, size_t ws_size,
                              hipStream_t stream) {
  const int*   stu_id  = (const int*)  d_in[0];
  const int*   exer_id = (const int*)  d_in[1];
  const float* kn_emb  = (const float*)d_in[2];
  const int*   ui1_u   = (const int*)  d_in[3];
  const int*   ui1_i   = (const int*)  d_in[4];
  const float* ui1_val = (const float*)d_in[5];
  const float* iu1_val = (const float*)d_in[6];
  const float* eps_ui1 = (const float*)d_in[7];
  const float* eps_iu1 = (const float*)d_in[8];
  const int*   ui0_u   = (const int*)  d_in[9];
  const int*   ui0_i   = (const int*)  d_in[10];
  const float* ui0_val = (const float*)d_in[11];
  const float* iu0_val = (const float*)d_in[12];
  const float* eps_ui0 = (const float*)d_in[13];
  const float* eps_iu0 = (const float*)d_in[14];
  const float* stu_emb = (const float*)d_in[15];
  const float* exe_emb = (const float*)d_in[16];
  const float* kno_emb = (const float*)d_in[17];
  const float* stu_b   = (const float*)d_in[18];
  const float* exe_b   = (const float*)d_in[19];
  const float* disc    = (const float*)d_in[20];
  const float* W1_l1   = (const float*)d_in[21];
  const float* b1_l1   = (const float*)d_in[22];
  const float* W2_l1   = (const float*)d_in[23];
  const float* b2_l1   = (const float*)d_in[24];
  const float* W1_l0   = (const float*)d_in[25];
  const float* b1_l0   = (const float*)d_in[26];
  const float* W2_l0   = (const float*)d_in[27];
  const float* b2_l0   = (const float*)d_in[28];
  const float* pw1     = (const float*)d_in[29];
  const float* pb1     = (const float*)d_in[30];
  const float* pw2     = (const float*)d_in[31];
  const float* pb2     = (const float*)d_in[32];
  const float* pw3     = (const float*)d_in[33];
  const float* pb3     = (const float*)d_in[34];
  float* out = (float*)d_out;
  (void)in_sizes; (void)n_in; (void)out_size; (void)ws_size;

  size_t off = 0;
  char* base = (char*)d_ws;
  auto carve = [&](size_t bytes) -> char* {
    char* p = base + off;
    off += (bytes + 255) & ~(size_t)255;
    return p;
  };
  unsigned int* w1f8_1 = (unsigned int*)carve(8192 * 4);
  unsigned int* w1f8_0 = (unsigned int*)carve(8192 * 4);
  float* pw1T = (float*)carve(32768 * 4);
  float* pw2T = (float*)carve(32768 * 4);
  float* pw3a = (float*)carve(128 * 4);
  float* keT  = (float*)carve(16384 * 4);
  // scratch; later the padded 4B S-records ((2*NE + BSLACK*NB_S) ints fits easily)
  char* vblock = carve((size_t)2 * NE_N * 8 + (size_t)BSLACK * NB_S * 8);
  // 4-deep bf16 layer tables (L0..L3) per side
  unsigned short* stuT0 = (unsigned short*)carve((size_t)S_N * 128 * 2);
  unsigned short* stuT1 = (unsigned short*)carve((size_t)S_N * 128 * 2);
  unsigned short* stuT2 = (unsigned short*)carve((size_t)S_N * 128 * 2);
  unsigned short* stuT3 = (unsigned short*)carve((size_t)S_N * 128 * 2);
  unsigned short* exeT0 = (unsigned short*)carve((size_t)E_N * 128 * 2);
  unsigned short* exeT1 = (unsigned short*)carve((size_t)E_N * 128 * 2);
  unsigned short* exeT2 = (unsigned short*)carve((size_t)E_N * 128 * 2);
  unsigned short* exeT3 = (unsigned short*)carve((size_t)E_N * 128 * 2);
  // sf8|ef8|logit1|logit0: contiguous 15.36 MB, all dead after append -> reused as sortCol tmp
  unsigned int* sf8 = (unsigned int*)carve((size_t)S_N * 32 * 4);
  unsigned int* ef8 = (unsigned int*)carve((size_t)E_N * 32 * 4);
  float* logit1 = (float*)carve((size_t)NE_N * 4);
  float* logit0 = (float*)carve((size_t)NE_N * 4);
  int* gHistS = (int*)carve((size_t)(NB_S + NB_E) * 4);
  int* gHistE = gHistS + NB_S;
  int* baseSb  = (int*)carve((size_t)(NB_S + 1) * 4);
  int* baseEb  = (int*)carve((size_t)(NB_E + 1) * 4);
  int* basePSb = (int*)carve((size_t)(NB_S + 1) * 4);
  int* basePEb = (int*)carve((size_t)(NB_E + 1) * 4);
  int* gCurS  = (int*)carve((size_t)NB_S * 4);
  int* gCurE  = (int*)carve((size_t)NB_E * 4);
  int2* recS = (int2*)carve((size_t)2 * NE_N * 8 + (size_t)BSLACK * NB_E * 8);
  int2* recE = (int2*)carve((size_t)2 * NE_N * 8);
  int* rowPtrS  = (int*)carve((size_t)S_N * 4);
  int* rowCnt8S = (int*)carve((size_t)S_N * 4);
  int* rowPtrE  = (int*)carve((size_t)E_N * 4);
  int* rowCnt8E = (int*)carve((size_t)E_N * 4);
  float* xbuf = (float*)carve((size_t)B_N * 128 * 4);
  int2* tmpRec = (int2*)sf8;    // 12.8 MB needed <= 15.36 MB contiguous dead region
  int*  rec4S  = (int*)vblock;  // padded 4B S-records
  int*  rec4E  = (int*)recS;    // recS dead after sortCol_S (stream-ordered); 7 MB fits

  prep_kernel<<<(98432 + 255) / 256, 256, 0, stream>>>(W1_l1, W1_l0, pw1, pw2, pw3, kno_emb,
                                                       w1f8_1, w1f8_0, pw1T, pw2T, pw3a, keT);
  init_bf_kernel<<<(2240000 + 255) / 256, 256, 0, stream>>>(stu_emb, exe_emb, stuT0, exeT0,
                                                            sf8, ef8);
  zero_kernel<<<(NB_S + NB_E + 255) / 256, 256, 0, stream>>>(gHistS, NB_S + NB_E);
  histB_kernel<<<(NE_N + 2047) / 2048, 256, 0, stream>>>(ui1_u, ui1_i, ui0_u, ui0_i,
                                                         gHistS, gHistE);
  scanB_kernel<<<1, 128, 0, stream>>>(gHistS, baseSb, gCurS, basePSb,
                                      gHistE, baseEb, gCurE, basePEb);
  gate_kernel<<<4096, 512, 0, stream>>>(ui1_u, ui1_i, ui0_u, ui0_i,
                                        (const unsigned char*)sf8, (const unsigned char*)ef8,
                                        (const unsigned char*)w1f8_1, (const unsigned char*)w1f8_0,
                                        b1_l1, W2_l1, b2_l1, b1_l0, W2_l0, b2_l0,
                                        logit1, logit0);
  append_kernel<<<(NE_N + 2047) / 2048, 256, 0, stream>>>(ui1_u, ui1_i, ui0_u, ui0_i,
                                                          logit1, logit0,
                                                          ui1_val, iu1_val, eps_ui1, eps_iu1,
                                                          ui0_val, iu0_val, eps_ui0, eps_iu0,
                                                          gCurS, gCurE, recS, recE);
  // S side: recS -> (col-sort) tmpRec -> (row-sort, 4B emit) rec4S
  sortCol_kernel<<<NB_S, 256, 0, stream>>>(baseSb, recS, tmpRec);
  sortRow_kernel<<<NB_S, 256, 0, stream>>>(baseSb, basePSb, tmpRec, rec4S,
                                           rowPtrS, rowCnt8S, S_N);
  // E side: recE -> tmpRec -> rec4E (overwrites dead recS region)
  sortCol_kernel<<<NB_E, 256, 0, stream>>>(baseEb, recE, tmpRec);
  sortRow_kernel<<<NB_E, 256, 0, stream>>>(baseEb, basePEb, tmpRec, rec4E,
                                           rowPtrE, rowCnt8E, E_N);
  unsigned short* stuT[4] = {stuT0, stuT1, stuT2, stuT3};
  unsigned short* exeT[4] = {exeT0, exeT1, exeT2, exeT3};
  for (int layer = 0; layer < L_N; ++layer) {
    spmm_csr_kernel<<<(S_N + E_N + 3) / 4, 256, 0, stream>>>(
        rowPtrS, rowCnt8S, rec4S, rowPtrE, rowCnt8E, rec4E,
        stuT[layer], exeT[layer], stuT[layer + 1], exeT[layer + 1]);
  }
  head1_kernel<<<B_N / 4, 256, 0, stream>>>(stu_id, exer_id, kn_emb,
                                            stuT0, stuT1, stuT2, stuT3,
                                            exeT0, exeT1, exeT2, exeT3,
                                            keT, stu_b, exe_b, disc, xbuf);
  head2_kernel<<<B_N / 4, 256, 0, stream>>>(xbuf, pw1T, pb1, pw2T, pb2, pw3a, pb3, out);
}

// Round 18
// 656.402 us; speedup vs baseline: 1.0276x; 1.0276x over previous
//
#include <hip/hip_runtime.h>
#include <hip/hip_bf16.h>
#include <math.h>

#define S_N 50000
#define E_N 20000
#define K_N 128
#define D_N 128
#define NE_N 800000
#define B_N 8192
#define L_N 3
#define GT32 (NE_N / 32)   // 25000 tiles of 32 edges per polarity
#define NB_S 782   // ceil(50000/64)
#define NB_E 313   // ceil(20000/64)
#define BPAD 464   // scan reserve base: per bucket p = (v+BPAD+15)&~15 <= v+479
#define BSLACK 480 // allocation slack per bucket (strictly > 479)

typedef __attribute__((ext_vector_type(4))) float floatx4;
typedef __attribute__((ext_vector_type(8))) short short8v;

__device__ __forceinline__ unsigned short f2bf(float x) {
  unsigned int u = __float_as_uint(x);
  u += 0x7FFFu + ((u >> 16) & 1u);
  return (unsigned short)(u >> 16);
}
__device__ __forceinline__ float bf2f(unsigned short u) {
  return __uint_as_float(((unsigned int)u) << 16);
}
__device__ __forceinline__ float sigm(float z) { return 1.0f / (1.0f + __expf(-z)); }

// OCP e4m3fn, round-to-nearest-even, saturating
__device__ __forceinline__ unsigned char f2e4m3(float x) {
  unsigned int u = __float_as_uint(x);
  unsigned char s = (unsigned char)((u >> 24) & 0x80);
  int e = (int)((u >> 23) & 0xFF) - 127;
  unsigned int m = u & 0x7FFFFF;
  if (((u >> 23) & 0xFF) == 0) return s;
  if (e >= 9) return s | 0x7E;
  if (e < -10) return s;
  if (e >= -6) {
    unsigned int keep = m >> 20;
    unsigned int rest = m & 0xFFFFF;
    if (rest > 0x80000u || (rest == 0x80000u && (keep & 1))) keep++;
    if (keep == 8) { keep = 0; e++; if (e >= 9) return s | 0x7E; }
    unsigned char b = (unsigned char)(s | ((e + 7) << 3) | keep);
    if ((b & 0x7F) == 0x7F) b = s | 0x7E;
    return b;
  }
  int shift = -6 - e;
  unsigned int full = 0x800000u | m;
  unsigned int q = full >> (20 + shift);
  unsigned int rest = full & ((1u << (20 + shift)) - 1);
  unsigned int half = 1u << (19 + shift);
  if (rest > half || (rest == half && (q & 1))) q++;
  if (q == 8) return s | 0x08;
  return (unsigned char)(s | q);
}
__device__ __forceinline__ unsigned int pk4_fp8(float4 v) {
  return (unsigned int)f2e4m3(v.x) | ((unsigned int)f2e4m3(v.y) << 8) |
         ((unsigned int)f2e4m3(v.z) << 16) | ((unsigned int)f2e4m3(v.w) << 24);
}

// ---------------- prep: fp8 W1s, |pw|^T, keT ----------------
__global__ void prep_kernel(const float* __restrict__ W1_l1, const float* __restrict__ W1_l0,
                            const float* __restrict__ pw1, const float* __restrict__ pw2,
                            const float* __restrict__ pw3, const float* __restrict__ ke,
                            unsigned int* __restrict__ w1f8_1, unsigned int* __restrict__ w1f8_0,
                            float* __restrict__ pw1T, float* __restrict__ pw2T,
                            float* __restrict__ pw3a, float* __restrict__ keT) {
  int i = blockIdx.x * blockDim.x + threadIdx.x;
  if (i < 8192) { w1f8_1[i] = pk4_fp8(((const float4*)W1_l1)[i]); return; }
  i -= 8192;
  if (i < 8192) { w1f8_0[i] = pk4_fp8(((const float4*)W1_l0)[i]); return; }
  i -= 8192;
  if (i < 32768) { int d = i >> 8, j = i & 255; pw1T[i] = fabsf(pw1[j * 128 + d]); return; }
  i -= 32768;
  if (i < 32768) { int d = i >> 7, j = i & 127; pw2T[i] = fabsf(pw2[j * 256 + d]); return; }
  i -= 32768;
  if (i < 128) { pw3a[i] = fabsf(pw3[i]); return; }
  i -= 128;
  if (i < 16384) { int d = i >> 7, k = i & 127; keT[i] = ke[k * 128 + d]; return; }
}

// ---------------- init: bf16 tables (spmm L0) + fp8 tables (gate) ----------------
__global__ void init_bf_kernel(const float* __restrict__ se, const float* __restrict__ ee,
                               unsigned short* __restrict__ sbf, unsigned short* __restrict__ ebf,
                               unsigned int* __restrict__ sf8, unsigned int* __restrict__ ef8) {
  int i = blockIdx.x * blockDim.x + threadIdx.x;
  const int nS4 = S_N * 32, nE4 = E_N * 32;
  if (i < nS4) {
    float4 v = ((const float4*)se)[i];
    unsigned int lo = (unsigned int)f2bf(v.x) | ((unsigned int)f2bf(v.y) << 16);
    unsigned int hi = (unsigned int)f2bf(v.z) | ((unsigned int)f2bf(v.w) << 16);
    ((uint2*)sbf)[i] = make_uint2(lo, hi);
    sf8[i] = pk4_fp8(v);
    return;
  }
  i -= nS4;
  if (i < nE4) {
    float4 v = ((const float4*)ee)[i];
    unsigned int lo = (unsigned int)f2bf(v.x) | ((unsigned int)f2bf(v.y) << 16);
    unsigned int hi = (unsigned int)f2bf(v.z) | ((unsigned int)f2bf(v.w) << 16);
    ((uint2*)ebf)[i] = make_uint2(lo, hi);
    ef8[i] = pk4_fp8(v);
  }
}

__global__ void zero_kernel(int* __restrict__ p, int n) {
  int i = blockIdx.x * blockDim.x + threadIdx.x;
  if (i < n) p[i] = 0;
}

// ---------------- bucket histogram (64-row buckets) ----------------
__global__ __launch_bounds__(256)
void histB_kernel(const int* __restrict__ u1, const int* __restrict__ i1,
                  const int* __restrict__ u0, const int* __restrict__ i0,
                  int* __restrict__ gHistS, int* __restrict__ gHistE) {
  __shared__ int hS[NB_S], hE[NB_E];
  int t = threadIdx.x;
  for (int b = t; b < NB_S; b += 256) hS[b] = 0;
  for (int b = t; b < NB_E; b += 256) hE[b] = 0;
  __syncthreads();
  int e0 = blockIdx.x * 2048;
  for (int k = 0; k < 8; ++k) {
    int e = e0 + k * 256 + t;
    if (e < NE_N) {
      atomicAdd(&hS[u1[e] >> 6], 1);
      atomicAdd(&hS[u0[e] >> 6], 1);
      atomicAdd(&hE[i1[e] >> 6], 1);
      atomicAdd(&hE[i0[e] >> 6], 1);
    }
  }
  __syncthreads();
  for (int b = t; b < NB_S; b += 256) if (hS[b]) atomicAdd(&gHistS[b], hS[b]);
  for (int b = t; b < NB_E; b += 256) if (hE[b]) atomicAdd(&gHistE[b], hE[b]);
}

// ------- scan buckets: packed bases+cursors AND padded-region bases -------
__global__ __launch_bounds__(128)
void scanB_kernel(const int* __restrict__ gHistS, int* __restrict__ baseS,
                  int* __restrict__ gCurS, int* __restrict__ basePS,
                  const int* __restrict__ gHistE, int* __restrict__ baseE,
                  int* __restrict__ gCurE, int* __restrict__ basePE) {
  int w = threadIdx.x >> 6, l = threadIdx.x & 63;
  int n = w ? NB_E : NB_S;
  const int* src = w ? gHistE : gHistS;
  int* bs  = w ? baseE  : baseS;
  int* cur = w ? gCurE  : gCurS;
  int* bsP = w ? basePE : basePS;
  int carry = 0, carryP = 0;
  for (int base = 0; base < n; base += 64) {
    int i = base + l;
    int v = (i < n) ? src[i] : 0;
    int p = (i < n) ? ((v + BPAD + 15) & ~15) : 0;
    int x = v, y = p;
#pragma unroll
    for (int o = 1; o < 64; o <<= 1) {
      int xx = __shfl_up(x, o, 64);
      int yy = __shfl_up(y, o, 64);
      if (l >= o) { x += xx; y += yy; }
    }
    if (i < n) {
      int ex = carry + x - v;
      bs[i] = ex; cur[i] = ex;
      bsP[i] = carryP + y - p;
    }
    carry += __shfl(x, 63, 64);
    carryP += __shfl(y, 63, 64);
  }
  if (l == 0) { bs[n] = carry; bsP[n] = carryP; }
}

// ------- edge gate: 256-thread blocks, 32-edge tiles, double-buffered -------
// 4 waves/block: wave w -> edge-half (w&1)*16, col-half (w>>1)*64. Same math as before,
// but 3-4x more independent barrier groups per CU (smaller blocks, less lockstep).
__global__ __launch_bounds__(256, 4)
void gate_kernel(const int* __restrict__ eu1, const int* __restrict__ ei1,
                 const int* __restrict__ eu0, const int* __restrict__ ei0,
                 const unsigned char* __restrict__ sf8, const unsigned char* __restrict__ ef8,
                 const unsigned char* __restrict__ w1f8_1, const unsigned char* __restrict__ w1f8_0,
                 const float* __restrict__ b1_1, const float* __restrict__ w2_1,
                 const float* __restrict__ b2_1,
                 const float* __restrict__ b1_0, const float* __restrict__ w2_0,
                 const float* __restrict__ b2_0,
                 float* __restrict__ logit1, float* __restrict__ logit0) {
  __shared__ unsigned char Xl[2][32 * 272];
  __shared__ float plds[4][16];
  const int* eu; const int* ei; const unsigned char* w1f8;
  const float *b1p, *w2p, *b2p; float* lg;
  if (blockIdx.x < 4096) {
    eu = eu1; ei = ei1; w1f8 = w1f8_1; b1p = b1_1; w2p = w2_1; b2p = b2_1; lg = logit1;
  } else {
    eu = eu0; ei = ei0; w1f8 = w1f8_0; b1p = b1_0; w2p = w2_0; b2p = b2_0; lg = logit0;
  }
  int bb = blockIdx.x & 4095;
  int t = threadIdx.x;
  int wv = t >> 6, l = t & 63;
  int sub = l & 15, grp = l >> 4;
  int eh = wv & 1, nh = wv >> 1;
  int el = t >> 3, q = t & 7;

  long bfrag[4][8];
#pragma unroll
  for (int nt = 0; nt < 4; ++nt) {
    int col = nh * 64 + nt * 16 + sub;
#pragma unroll
    for (int ks = 0; ks < 8; ++ks)
      bfrag[nt][ks] = *(const long*)&w1f8[(col << 8) + ks * 32 + grp * 8];
  }
  float b1v[4], w2v[4];
#pragma unroll
  for (int nt = 0; nt < 4; ++nt) {
    int col = nh * 64 + nt * 16 + sub;
    b1v[nt] = b1p[col];
    w2v[nt] = w2p[col];
  }
  float b2s = b2p[0];

  uint4 c0, c1;
  {  // prologue: stage tile bb into buffer 0 (32 edges x 256B, thread t -> edge t>>3, chunk t&7)
    int eIdx = bb * 32 + el;
    const unsigned char* srcrow = (q < 4)
        ? sf8 + (size_t)eu[eIdx] * 128 + q * 32
        : ef8 + (size_t)ei[eIdx] * 128 + (q - 4) * 32;
    c0 = ((const uint4*)srcrow)[0];
    c1 = ((const uint4*)srcrow)[1];
    *(uint4*)&Xl[0][el * 272 + q * 32] = c0;
    *(uint4*)&Xl[0][el * 272 + q * 32 + 16] = c1;
  }
  int parity = 0;
  for (int tile = bb; tile < GT32; tile += 4096) {
    int nxt = tile + 4096;
    bool hasNext = (nxt < GT32);
    if (hasNext) {  // issue next tile's gathers early: latency hides under MFMA below
      int eIdx = nxt * 32 + el;
      const unsigned char* srcrow = (q < 4)
          ? sf8 + (size_t)eu[eIdx] * 128 + q * 32
          : ef8 + (size_t)ei[eIdx] * 128 + (q - 4) * 32;
      c0 = ((const uint4*)srcrow)[0];
      c1 = ((const uint4*)srcrow)[1];
    }
    __syncthreads();   // Xl[parity] fully staged

    floatx4 zero4 = {0.f, 0.f, 0.f, 0.f};
    floatx4 acc[4] = {zero4, zero4, zero4, zero4};
#pragma unroll
    for (int ks = 0; ks < 8; ++ks) {
      long a = *(const long*)&Xl[parity][(eh * 16 + sub) * 272 + ks * 32 + grp * 8];
#pragma unroll
      for (int nt = 0; nt < 4; ++nt)
        acc[nt] = __builtin_amdgcn_mfma_f32_16x16x32_fp8_fp8(a, bfrag[nt][ks], acc[nt], 0, 0, 0);
    }
    float p0 = 0, p1 = 0, p2 = 0, p3 = 0;
#pragma unroll
    for (int nt = 0; nt < 4; ++nt) {
      float bb2 = b1v[nt], ww = w2v[nt];
      p0 += fmaxf(acc[nt][0] + bb2, 0.0f) * ww;
      p1 += fmaxf(acc[nt][1] + bb2, 0.0f) * ww;
      p2 += fmaxf(acc[nt][2] + bb2, 0.0f) * ww;
      p3 += fmaxf(acc[nt][3] + bb2, 0.0f) * ww;
    }
#pragma unroll
    for (int m = 1; m < 16; m <<= 1) {   // sum over the 16 W1-cols in each 16-lane group
      p0 += __shfl_xor(p0, m, 64);
      p1 += __shfl_xor(p1, m, 64);
      p2 += __shfl_xor(p2, m, 64);
      p3 += __shfl_xor(p3, m, 64);
    }
    if (sub < 4) {   // edge (within wave's 16) = grp*4 + sub; value = p_sub
      float pv = (sub == 0) ? p0 : (sub == 1) ? p1 : (sub == 2) ? p2 : p3;
      plds[wv][grp * 4 + sub] = pv;
    }
    __syncthreads();   // plds ready; all reads of Xl[parity] done
    if (wv == 0 && l < 32)   // edge E = l: halves from waves (E>>4) and 2+(E>>4)
      lg[tile * 32 + l] = plds[l >> 4][l & 15] + plds[2 + (l >> 4)][l & 15] + b2s;
    if (hasNext) {     // write staged regs into the other buffer
      *(uint4*)&Xl[parity ^ 1][el * 272 + q * 32] = c0;
      *(uint4*)&Xl[parity ^ 1][el * 272 + q * 32 + 16] = c1;
    }
    parity ^= 1;
  }
}

// ------- append (gatefin fused): compute v inline from logit/eps/val, bucket-append -------
__global__ __launch_bounds__(256)
void append_kernel(const int* __restrict__ u1, const int* __restrict__ i1,
                   const int* __restrict__ u0, const int* __restrict__ i0,
                   const float* __restrict__ logit1, const float* __restrict__ logit0,
                   const float* __restrict__ ui1_val, const float* __restrict__ iu1_val,
                   const float* __restrict__ eps_ui1, const float* __restrict__ eps_iu1,
                   const float* __restrict__ ui0_val, const float* __restrict__ iu0_val,
                   const float* __restrict__ eps_ui0, const float* __restrict__ eps_iu0,
                   int* __restrict__ gCurS, int* __restrict__ gCurE,
                   int2* __restrict__ recS, int2* __restrict__ recE) {
  __shared__ int hS[NB_S], hE[NB_E];
  int t = threadIdx.x;
  for (int b = t; b < NB_S; b += 256) hS[b] = 0;
  for (int b = t; b < NB_E; b += 256) hE[b] = 0;
  __syncthreads();
  int e0 = blockIdx.x * 2048;
  for (int k = 0; k < 8; ++k) {
    int e = e0 + k * 256 + t;
    if (e < NE_N) {
      atomicAdd(&hS[u1[e] >> 6], 1);
      atomicAdd(&hS[u0[e] >> 6], 1);
      atomicAdd(&hE[i1[e] >> 6], 1);
      atomicAdd(&hE[i0[e] >> 6], 1);
    }
  }
  __syncthreads();
  for (int b = t; b < NB_S; b += 256) { int c = hS[b]; hS[b] = c ? atomicAdd(&gCurS[b], c) : 0; }
  for (int b = t; b < NB_E; b += 256) { int c = hE[b]; hE[b] = c ? atomicAdd(&gCurE[b], c) : 0; }
  __syncthreads();
  for (int k = 0; k < 8; ++k) {
    int e = e0 + k * 256 + t;
    if (e < NE_N) {
      int a = u1[e], b = i1[e], c = u0[e], d = i0[e];
      float lg1 = logit1[e], lg0 = logit0[e];
      float ep, g, s2;
      ep = fminf(fmaxf(eps_ui1[e], 1e-6f), 1.0f - 1e-6f);
      g = __logf(ep) - log1pf(-ep);
      s2 = 1.0f / (1.0f + __expf(-(lg1 + g) * 5.0f));
      float v_ui1 = ui1_val[e] * (0.3f * s2 + 0.7f);
      ep = fminf(fmaxf(eps_iu1[e], 1e-6f), 1.0f - 1e-6f);
      g = __logf(ep) - log1pf(-ep);
      s2 = 1.0f / (1.0f + __expf(-(lg1 + g) * 5.0f));
      float v_iu1 = iu1_val[e] * (0.3f * s2 + 0.7f);
      ep = fminf(fmaxf(eps_ui0[e], 1e-6f), 1.0f - 1e-6f);
      g = __logf(ep) - log1pf(-ep);
      s2 = 1.0f / (1.0f + __expf(-(lg0 + g) * 5.0f));
      float v_ui0 = ui0_val[e] * (0.3f * s2 + 0.7f);
      ep = fminf(fmaxf(eps_iu0[e], 1e-6f), 1.0f - 1e-6f);
      g = __logf(ep) - log1pf(-ep);
      s2 = 1.0f / (1.0f + __expf(-(lg0 + g) * 5.0f));
      float v_iu0 = iu0_val[e] * (0.3f * s2 + 0.7f);
      int s;
      s = atomicAdd(&hS[a >> 6], 1); recS[s] = make_int2(((a & 63) << 16) | b, __float_as_int(v_ui1));
      s = atomicAdd(&hE[b >> 6], 1); recE[s] = make_int2(((b & 63) << 16) | a, __float_as_int(v_iu1));
      s = atomicAdd(&hS[c >> 6], 1); recS[s] = make_int2(((c & 63) << 16) | d, __float_as_int(v_ui0));
      s = atomicAdd(&hE[d >> 6], 1); recE[s] = make_int2(((d & 63) << 16) | c, __float_as_int(v_iu0));
    }
  }
}

// ---- per-bucket counting sort by dst ROW into padded per-row segments (once) ----
__global__ __launch_bounds__(256)
void sortRow_kernel(const int* __restrict__ baseIn, const int* __restrict__ basePad,
                    const int2* __restrict__ rin_all, int2* __restrict__ rout_all,
                    int* __restrict__ rowPtr, int* __restrict__ rowCnt8, int nRowsTot) {
  __shared__ int cntR[64], offR[64], curR[64];
  int b = blockIdx.x, t = threadIdx.x;
  int bi = baseIn[b], cnt = baseIn[b + 1] - bi;
  int bo = basePad[b];
  int row0 = b * 64;
  const int2* rin = rin_all + bi;
  int2* rout = rout_all + bo;
  if (t < 64) cntR[t] = 0;
  __syncthreads();
  for (int j = t; j < cnt; j += 256) atomicAdd(&cntR[(rin[j].x >> 16) & 63], 1);
  __syncthreads();
  if (t < 64) {
    int p = (cntR[t] + 7) & ~7;
    int x = p;
#pragma unroll
    for (int o = 1; o < 64; o <<= 1) { int y = __shfl_up(x, o, 64); if (t >= o) x += y; }
    int ex = x - p;
    offR[t] = ex; curR[t] = ex;
    if (row0 + t < nRowsTot) {
      rowPtr[row0 + t] = bo + ex;
      rowCnt8[row0 + t] = p >> 3;
    }
  }
  __syncthreads();
  for (int j = t; j < cnt; j += 256) {
    int2 rc = rin[j];
    int r = (rc.x >> 16) & 63;
    int slot = atomicAdd(&curR[r], 1);
    rout[slot] = make_int2(rc.x & 0xFFFF, rc.y);
  }
  __syncthreads();
  if (t < 64) {
    int c = cntR[t], p = (c + 7) & ~7, o = offR[t];
    for (int j = c; j < p; ++j) rout[o + j] = make_int2(0, 0);
  }
}

// ---- spmm CSR bf16 (proven): wave per dst row, 8 records in flight; no sum RMW ----
__global__ __launch_bounds__(256)
void spmm_csr_kernel(const int* __restrict__ rowPtrS, const int* __restrict__ rowCnt8S,
                     const int2* __restrict__ rec2S,
                     const int* __restrict__ rowPtrE, const int* __restrict__ rowCnt8E,
                     const int2* __restrict__ rec2E,
                     const unsigned short* __restrict__ scur, const unsigned short* __restrict__ ecur,
                     unsigned short* __restrict__ snxt, unsigned short* __restrict__ enxt) {
  int gw = (blockIdx.x * 256 + threadIdx.x) >> 6;
  int l = threadIdx.x & 63;
  int g = l >> 3, lane8 = l & 7;
  if (gw >= S_N + E_N) return;
  const int2* rec; const unsigned short* src; unsigned short* dst;
  const int* rp; const int* rc8; int r;
  if (gw < S_N) { r = gw;       rp = rowPtrS; rc8 = rowCnt8S; rec = rec2S; src = ecur; dst = snxt; }
  else          { r = gw - S_N; rp = rowPtrE; rc8 = rowCnt8E; rec = rec2E; src = scur; dst = enxt; }
  int s0 = rp[r], n8 = rc8[r];
  float acc[16];
#pragma unroll
  for (int i = 0; i < 16; ++i) acc[i] = 0.f;
  for (int k = 0; k < n8; ++k) {
    int2 e = rec[s0 + k * 8 + g];
    float val = __int_as_float(e.y);
    const uint4* rowp = (const uint4*)(src + (size_t)e.x * 128);
    uint4 q0 = rowp[lane8 * 2];
    uint4 q1 = rowp[lane8 * 2 + 1];
#pragma unroll
    for (int i = 0; i < 4; ++i) {
      unsigned int w = ((const unsigned int*)&q0)[i];
      acc[2 * i]     = fmaf(val, bf2f((unsigned short)(w & 0xFFFF)), acc[2 * i]);
      acc[2 * i + 1] = fmaf(val, bf2f((unsigned short)(w >> 16)),    acc[2 * i + 1]);
    }
#pragma unroll
    for (int i = 0; i < 4; ++i) {
      unsigned int w = ((const unsigned int*)&q1)[i];
      acc[8 + 2 * i]     = fmaf(val, bf2f((unsigned short)(w & 0xFFFF)), acc[8 + 2 * i]);
      acc[8 + 2 * i + 1] = fmaf(val, bf2f((unsigned short)(w >> 16)),    acc[8 + 2 * i + 1]);
    }
  }
#pragma unroll
  for (int m = 8; m < 64; m <<= 1) {
#pragma unroll
    for (int i = 0; i < 16; ++i) acc[i] += __shfl_xor(acc[i], m, 64);
  }
  if (g == 0) {
    size_t base = (size_t)r * 128 + lane8 * 16;
    short8v o0, o1;
#pragma unroll
    for (int i = 0; i < 8; ++i) { o0[i] = (short)f2bf(acc[i]); o1[i] = (short)f2bf(acc[8 + i]); }
    *(short8v*)(dst + base) = o0;
    *(short8v*)(dst + base + 8) = o1;
  }
}

// ------- head 1: gather-sum 4 bf16 layer tables per side -------
__global__ __launch_bounds__(256)
void head1_kernel(const int* __restrict__ stu_id, const int* __restrict__ exer_id,
                  const float* __restrict__ kn,
                  const unsigned short* __restrict__ sT0, const unsigned short* __restrict__ sT1,
                  const unsigned short* __restrict__ sT2, const unsigned short* __restrict__ sT3,
                  const unsigned short* __restrict__ eT0, const unsigned short* __restrict__ eT1,
                  const unsigned short* __restrict__ eT2, const unsigned short* __restrict__ eT3,
                  const float* __restrict__ keT,
                  const float* __restrict__ stub, const float* __restrict__ exeb,
                  const float* __restrict__ disc, float* __restrict__ xbuf) {
  __shared__ float srw[4][128], erw[4][128];
  int wv = threadIdx.x >> 6, l = threadIdx.x & 63;
  int b = blockIdx.x * 4 + wv;
  int sid = stu_id[b], eid = exer_id[b];
  size_t so = (size_t)sid * 128, eo = (size_t)eid * 128;
  float sx = 0.f, sy = 0.f, ex = 0.f, ey = 0.f;
  unsigned int w;
  w = ((const unsigned int*)(sT0 + so))[l]; sx += bf2f((unsigned short)(w & 0xFFFF)); sy += bf2f((unsigned short)(w >> 16));
  w = ((const unsigned int*)(sT1 + so))[l]; sx += bf2f((unsigned short)(w & 0xFFFF)); sy += bf2f((unsigned short)(w >> 16));
  w = ((const unsigned int*)(sT2 + so))[l]; sx += bf2f((unsigned short)(w & 0xFFFF)); sy += bf2f((unsigned short)(w >> 16));
  w = ((const unsigned int*)(sT3 + so))[l]; sx += bf2f((unsigned short)(w & 0xFFFF)); sy += bf2f((unsigned short)(w >> 16));
  w = ((const unsigned int*)(eT0 + eo))[l]; ex += bf2f((unsigned short)(w & 0xFFFF)); ey += bf2f((unsigned short)(w >> 16));
  w = ((const unsigned int*)(eT1 + eo))[l]; ex += bf2f((unsigned short)(w & 0xFFFF)); ey += bf2f((unsigned short)(w >> 16));
  w = ((const unsigned int*)(eT2 + eo))[l]; ex += bf2f((unsigned short)(w & 0xFFFF)); ey += bf2f((unsigned short)(w >> 16));
  w = ((const unsigned int*)(eT3 + eo))[l]; ex += bf2f((unsigned short)(w & 0xFFFF)); ey += bf2f((unsigned short)(w >> 16));
  srw[wv][2 * l] = sx * 0.25f; srw[wv][2 * l + 1] = sy * 0.25f;
  erw[wv][2 * l] = ex * 0.25f; erw[wv][2 * l + 1] = ey * 0.25f;
  __syncthreads();
  float s0 = 0, s1 = 0, d0 = 0, d1 = 0;
  for (int d = 0; d < 128; ++d) {
    float sd = srw[wv][d], ed = erw[wv][d];
    float ka = keT[d * 128 + l], kb = keT[d * 128 + l + 64];
    s0 = fmaf(sd, ka, s0); s1 = fmaf(sd, kb, s1);
    d0 = fmaf(ed, ka, d0); d1 = fmaf(ed, kb, d1);
  }
  float sbv = stub[sid], ebv = exeb[eid];
  float edv = sigm(disc[eid]);
  float st0 = sigm(s0 + sbv), st1 = sigm(s1 + sbv);
  float df0 = sigm(d0 + ebv), df1 = sigm(d1 + ebv);
  xbuf[(size_t)b * 128 + l]      = edv * (st0 - df0) * kn[(size_t)b * 128 + l];
  xbuf[(size_t)b * 128 + l + 64] = edv * (st1 - df1) * kn[(size_t)b * 128 + l + 64];
}

// ---------------- head 2: PosLinear MLP ----------------
__global__ __launch_bounds__(256)
void head2_kernel(const float* __restrict__ xbuf, const float* __restrict__ pw1T,
                  const float* __restrict__ pb1, const float* __restrict__ pw2T,
                  const float* __restrict__ pb2, const float* __restrict__ pw3a,
                  const float* __restrict__ pb3, float* __restrict__ out) {
  __shared__ float xs[4][128], h1s[4][256], h2s[4][128];
  int wv = threadIdx.x >> 6, l = threadIdx.x & 63;
  int b = blockIdx.x * 4 + wv;
  xs[wv][l] = xbuf[(size_t)b * 128 + l];
  xs[wv][l + 64] = xbuf[(size_t)b * 128 + l + 64];
  __syncthreads();
#pragma unroll
  for (int q = 0; q < 4; ++q) {
    int j = q * 64 + l;
    float acc = 0.f;
    for (int d = 0; d < 128; ++d) acc = fmaf(xs[wv][d], pw1T[d * 256 + j], acc);
    h1s[wv][j] = sigm(acc + pb1[j]);
  }
  __syncthreads();
#pragma unroll
  for (int q = 0; q < 2; ++q) {
    int j = q * 64 + l;
    float acc = 0.f;
    for (int d = 0; d < 256; ++d) acc = fmaf(h1s[wv][d], pw2T[d * 128 + j], acc);
    h2s[wv][j] = sigm(acc + pb2[j]);
  }
  __syncthreads();
  float p = h2s[wv][l] * pw3a[l] + h2s[wv][l + 64] * pw3a[l + 64];
#pragma unroll
  for (int m = 1; m < 64; m <<= 1) p += __shfl_xor(p, m, 64);
  if (l == 0) out[b] = sigm(p + pb3[0]);
}

extern "C" void kernel_launch(void* const* d_in, const int* in_sizes, int n_in,
                              void* d_out, int out_size, void* d_ws, size_t ws_size,
                              hipStream_t stream) {
  const int*   stu_id  = (const int*)  d_in[0];
  const int*   exer_id = (const int*)  d_in[1];
  const float* kn_emb  = (const float*)d_in[2];
  const int*   ui1_u   = (const int*)  d_in[3];
  const int*   ui1_i   = (const int*)  d_in[4];
  const float* ui1_val = (const float*)d_in[5];
  const float* iu1_val = (const float*)d_in[6];
  const float* eps_ui1 = (const float*)d_in[7];
  const float* eps_iu1 = (const float*)d_in[8];
  const int*   ui0_u   = (const int*)  d_in[9];
  const int*   ui0_i   = (const int*)  d_in[10];
  const float* ui0_val = (const float*)d_in[11];
  const float* iu0_val = (const float*)d_in[12];
  const float* eps_ui0 = (const float*)d_in[13];
  const float* eps_iu0 = (const float*)d_in[14];
  const float* stu_emb = (const float*)d_in[15];
  const float* exe_emb = (const float*)d_in[16];
  const float* kno_emb = (const float*)d_in[17];
  const float* stu_b   = (const float*)d_in[18];
  const float* exe_b   = (const float*)d_in[19];
  const float* disc    = (const float*)d_in[20];
  const float* W1_l1   = (const float*)d_in[21];
  const float* b1_l1   = (const float*)d_in[22];
  const float* W2_l1   = (const float*)d_in[23];
  const float* b2_l1   = (const float*)d_in[24];
  const float* W1_l0   = (const float*)d_in[25];
  const float* b1_l0   = (const float*)d_in[26];
  const float* W2_l0   = (const float*)d_in[27];
  const float* b2_l0   = (const float*)d_in[28];
  const float* pw1     = (const float*)d_in[29];
  const float* pb1     = (const float*)d_in[30];
  const float* pw2     = (const float*)d_in[31];
  const float* pb2     = (const float*)d_in[32];
  const float* pw3     = (const float*)d_in[33];
  const float* pb3     = (const float*)d_in[34];
  float* out = (float*)d_out;
  (void)in_sizes; (void)n_in; (void)out_size; (void)ws_size;

  size_t off = 0;
  char* base = (char*)d_ws;
  auto carve = [&](size_t bytes) -> char* {
    char* p = base + off;
    off += (bytes + 255) & ~(size_t)255;
    return p;
  };
  unsigned int* w1f8_1 = (unsigned int*)carve(8192 * 4);
  unsigned int* w1f8_0 = (unsigned int*)carve(8192 * 4);
  float* pw1T = (float*)carve(32768 * 4);
  float* pw2T = (float*)carve(32768 * 4);
  float* pw3a = (float*)carve(128 * 4);
  float* keT  = (float*)carve(16384 * 4);
  // scratch region later used as padded sorted S records (2*NE + BSLACK*NB_S) int2
  char* vblock = carve((size_t)2 * NE_N * 8 + (size_t)BSLACK * NB_S * 8);
  // 4-deep bf16 layer tables (L0..L3) per side
  unsigned short* stuT0 = (unsigned short*)carve((size_t)S_N * 128 * 2);
  unsigned short* stuT1 = (unsigned short*)carve((size_t)S_N * 128 * 2);
  unsigned short* stuT2 = (unsigned short*)carve((size_t)S_N * 128 * 2);
  unsigned short* stuT3 = (unsigned short*)carve((size_t)S_N * 128 * 2);
  unsigned short* exeT0 = (unsigned short*)carve((size_t)E_N * 128 * 2);
  unsigned short* exeT1 = (unsigned short*)carve((size_t)E_N * 128 * 2);
  unsigned short* exeT2 = (unsigned short*)carve((size_t)E_N * 128 * 2);
  unsigned short* exeT3 = (unsigned short*)carve((size_t)E_N * 128 * 2);
  unsigned int* sf8 = (unsigned int*)carve((size_t)S_N * 32 * 4);
  unsigned int* ef8 = (unsigned int*)carve((size_t)E_N * 32 * 4);
  float* logit1 = (float*)carve((size_t)NE_N * 4);
  float* logit0 = (float*)carve((size_t)NE_N * 4);
  int* gHistS = (int*)carve((size_t)(NB_S + NB_E) * 4);
  int* gHistE = gHistS + NB_S;
  int* baseSb  = (int*)carve((size_t)(NB_S + 1) * 4);
  int* baseEb  = (int*)carve((size_t)(NB_E + 1) * 4);
  int* basePSb = (int*)carve((size_t)(NB_S + 1) * 4);
  int* basePEb = (int*)carve((size_t)(NB_E + 1) * 4);
  int* gCurS  = (int*)carve((size_t)NB_S * 4);
  int* gCurE  = (int*)carve((size_t)NB_E * 4);
  int2* recS = (int2*)carve((size_t)2 * NE_N * 8 + (size_t)BSLACK * NB_E * 8);
  int2* recE = (int2*)carve((size_t)2 * NE_N * 8);
  int* rowPtrS  = (int*)carve((size_t)S_N * 4);
  int* rowCnt8S = (int*)carve((size_t)S_N * 4);
  int* rowPtrE  = (int*)carve((size_t)E_N * 4);
  int* rowCnt8E = (int*)carve((size_t)E_N * 4);
  float* xbuf = (float*)carve((size_t)B_N * 128 * 4);
  int2* rec2S = (int2*)vblock;  // scratch free until sortRow_S
  int2* rec2E = recS;           // recS dead after sortRow_S (stream-ordered)

  prep_kernel<<<(98432 + 255) / 256, 256, 0, stream>>>(W1_l1, W1_l0, pw1, pw2, pw3, kno_emb,
                                                       w1f8_1, w1f8_0, pw1T, pw2T, pw3a, keT);
  init_bf_kernel<<<(2240000 + 255) / 256, 256, 0, stream>>>(stu_emb, exe_emb, stuT0, exeT0,
                                                            sf8, ef8);
  zero_kernel<<<(NB_S + NB_E + 255) / 256, 256, 0, stream>>>(gHistS, NB_S + NB_E);
  histB_kernel<<<(NE_N + 2047) / 2048, 256, 0, stream>>>(ui1_u, ui1_i, ui0_u, ui0_i,
                                                         gHistS, gHistE);
  scanB_kernel<<<1, 128, 0, stream>>>(gHistS, baseSb, gCurS, basePSb,
                                      gHistE, baseEb, gCurE, basePEb);
  gate_kernel<<<8192, 256, 0, stream>>>(ui1_u, ui1_i, ui0_u, ui0_i,
                                        (const unsigned char*)sf8, (const unsigned char*)ef8,
                                        (const unsigned char*)w1f8_1, (const unsigned char*)w1f8_0,
                                        b1_l1, W2_l1, b2_l1, b1_l0, W2_l0, b2_l0,
                                        logit1, logit0);
  append_kernel<<<(NE_N + 2047) / 2048, 256, 0, stream>>>(ui1_u, ui1_i, ui0_u, ui0_i,
                                                          logit1, logit0,
                                                          ui1_val, iu1_val, eps_ui1, eps_iu1,
                                                          ui0_val, iu0_val, eps_ui0, eps_iu0,
                                                          gCurS, gCurE, recS, recE);
  sortRow_kernel<<<NB_S, 256, 0, stream>>>(baseSb, basePSb, recS, rec2S,
                                           rowPtrS, rowCnt8S, S_N);
  sortRow_kernel<<<NB_E, 256, 0, stream>>>(baseEb, basePEb, recE, rec2E,
                                           rowPtrE, rowCnt8E, E_N);
  unsigned short* stuT[4] = {stuT0, stuT1, stuT2, stuT3};
  unsigned short* exeT[4] = {exeT0, exeT1, exeT2, exeT3};
  for (int layer = 0; layer < L_N; ++layer) {
    spmm_csr_kernel<<<(S_N + E_N + 3) / 4, 256, 0, stream>>>(
        rowPtrS, rowCnt8S, rec2S, rowPtrE, rowCnt8E, rec2E,
        stuT[layer], exeT[layer], stuT[layer + 1], exeT[layer + 1]);
  }
  head1_kernel<<<B_N / 4, 256, 0, stream>>>(stu_id, exer_id, kn_emb,
                                            stuT0, stuT1, stuT2, stuT3,
                                            exeT0, exeT1, exeT2, exeT3,
                                            keT, stu_b, exe_b, disc, xbuf);
  head2_kernel<<<B_N / 4, 256, 0, stream>>>(xbuf, pw1T, pb1, pw2T, pb2, pw3a, pb3, out);
}